// Round 1
// baseline (119.478 us; speedup 1.0000x reference)
//
#include <hip/hip_runtime.h>
#include <stdint.h>
#include <stddef.h>

#define BATCH 64
#define NN    1024
#define DD    64   // DIN == DOUT == 64

typedef _Float16 h8 __attribute__((ext_vector_type(8)));
typedef _Float16 h4 __attribute__((ext_vector_type(4)));
typedef float    f32x4 __attribute__((ext_vector_type(4)));

// XOR-swizzled granule slot: tiles are [rows][64 halfs] = [rows][8 granules of 16B].
// slot(row, gran) spreads the column-granules across banks (G4 / T2 pattern).
__device__ __forceinline__ int swz(int row, int gran) {
    return (row << 3) + (gran ^ (row & 7));
}

// ---------------- K0: weight -> WT (transposed, fp16), 64x64 ----------------
__global__ __launch_bounds__(256) void k_wt(const float* __restrict__ w,
                                            _Float16* __restrict__ wt) {
#pragma unroll
    for (int it = 0; it < 4; ++it) {
        const int idx = threadIdx.x + (it << 8);   // float4 index 0..1023
        const int k = idx >> 4, d4 = idx & 15;
        const float4 v = ((const float4*)w)[idx];
        wt[(d4 * 4 + 0) * DD + k] = (_Float16)v.x;
        wt[(d4 * 4 + 1) * DD + k] = (_Float16)v.y;
        wt[(d4 * 4 + 2) * DD + k] = (_Float16)v.z;
        wt[(d4 * 4 + 3) * DD + k] = (_Float16)v.w;
    }
}

// ---------------- K1: row degrees -> dinv; optionally adj+I -> fp16 ----------------
// One wave per row (4 rows per 256-thread block). Degrees use adj BEFORE self-loops.
__global__ __launch_bounds__(256) void k_deg(const float* __restrict__ adj,
                                             _Float16* __restrict__ adjh,
                                             float* __restrict__ dinv,
                                             int writeH) {
    const int lane = threadIdx.x & 63;
    const int rowg = blockIdx.x * 4 + (threadIdx.x >> 6);   // 0..65535
    const int i = rowg & (NN - 1);                          // row index within batch
    const float* rp = adj + (size_t)rowg * NN;
    float s = 0.f;
#pragma unroll
    for (int k = 0; k < 4; ++k) {
        const int f4 = lane + (k << 6);
        const float4 v = ((const float4*)rp)[f4];
        s += v.x + v.y + v.z + v.w;
        if (writeH) {
            const int j0 = f4 << 2;
            h4 o;
            o[0] = (_Float16)(v.x + ((j0 + 0) == i ? 1.f : 0.f));
            o[1] = (_Float16)(v.y + ((j0 + 1) == i ? 1.f : 0.f));
            o[2] = (_Float16)(v.z + ((j0 + 2) == i ? 1.f : 0.f));
            o[3] = (_Float16)(v.w + ((j0 + 3) == i ? 1.f : 0.f));
            ((h4*)(adjh + (size_t)rowg * NN))[f4] = o;
        }
    }
#pragma unroll
    for (int off = 32; off; off >>= 1) s += __shfl_xor(s, off);
    if (lane == 0) dinv[rowg] = 1.f / sqrtf(s);
}

// ---------------- K2: z^T[b][d][j] = dinv[j] * (att @ W)[j][d], fp16 ----------------
// MFMA 16x16x32 f16. Block: 128 j-rows x 64 d. A = att (staged fp32->fp16), B = W^T.
__global__ __launch_bounds__(256) void k_xw(const float* __restrict__ att,
                                            const _Float16* __restrict__ wt,
                                            const float* __restrict__ dinv,
                                            _Float16* __restrict__ zT) {
    __shared__ __align__(16) _Float16 attS[128 * 64];
    __shared__ __align__(16) _Float16 wtS[64 * 64];
    const int t = threadIdx.x;
    const int bb = blockIdx.y;
    const int j0 = blockIdx.x * 128;

    // stage att tile (fp32 -> fp16), 1024 granules of 8 halfs
#pragma unroll
    for (int it = 0; it < 4; ++it) {
        const int g = t + (it << 8);
        const int r = g >> 3, c = g & 7;
        const float4* p = (const float4*)(att + (size_t)(bb * NN + j0 + r) * DD + (c << 3));
        const float4 v0 = p[0], v1 = p[1];
        h8 o;
        o[0] = (_Float16)v0.x; o[1] = (_Float16)v0.y; o[2] = (_Float16)v0.z; o[3] = (_Float16)v0.w;
        o[4] = (_Float16)v1.x; o[5] = (_Float16)v1.y; o[6] = (_Float16)v1.z; o[7] = (_Float16)v1.w;
        *(h8*)&attS[swz(r, c) * 8] = o;
    }
    // stage WT tile (already fp16), 512 granules
#pragma unroll
    for (int it = 0; it < 2; ++it) {
        const int g = t + (it << 8);
        const int r = g >> 3, c = g & 7;
        const h8 v = *(const h8*)(wt + r * DD + (c << 3));
        *(h8*)&wtS[swz(r, c) * 8] = v;
    }
    __syncthreads();

    const int w = t >> 6, lane = t & 63;
    const int lr = lane & 15, lg = lane >> 4;
    const f32x4 zero = {0.f, 0.f, 0.f, 0.f};
    f32x4 acc[2][4];
#pragma unroll
    for (int mf = 0; mf < 2; ++mf)
#pragma unroll
        for (int nf = 0; nf < 4; ++nf) acc[mf][nf] = zero;

#pragma unroll
    for (int kk = 0; kk < 2; ++kk) {
        h8 a[2], bfr[4];
#pragma unroll
        for (int mf = 0; mf < 2; ++mf) {
            const int row = w * 32 + mf * 16 + lr;
            a[mf] = *(const h8*)&attS[swz(row, kk * 4 + lg) * 8];
        }
#pragma unroll
        for (int nf = 0; nf < 4; ++nf) {
            const int row = nf * 16 + lr;
            bfr[nf] = *(const h8*)&wtS[swz(row, kk * 4 + lg) * 8];
        }
#pragma unroll
        for (int mf = 0; mf < 2; ++mf)
#pragma unroll
            for (int nf = 0; nf < 4; ++nf)
                acc[mf][nf] = __builtin_amdgcn_mfma_f32_16x16x32_f16(a[mf], bfr[nf], acc[mf][nf], 0, 0, 0);
    }

    // epilogue: scale by dinv[j] (fp32), store transposed zT[b][d][j] as fp16.
    // D layout: col(d) = lane&15, row(j) = (lane>>4)*4 + reg  -> lane's 4 regs are
    // 4 consecutive j at fixed d -> pack into one 8B store.
#pragma unroll
    for (int mf = 0; mf < 2; ++mf) {
        const int jb = j0 + w * 32 + mf * 16 + lg * 4;
        const float4 dv = *(const float4*)&dinv[bb * NN + jb];
#pragma unroll
        for (int nf = 0; nf < 4; ++nf) {
            const int d = nf * 16 + lr;
            h4 o;
            o[0] = (_Float16)(acc[mf][nf][0] * dv.x);
            o[1] = (_Float16)(acc[mf][nf][1] * dv.y);
            o[2] = (_Float16)(acc[mf][nf][2] * dv.z);
            o[3] = (_Float16)(acc[mf][nf][3] * dv.w);
            *(h4*)(zT + (size_t)(bb * DD + d) * NN + jb) = o;
        }
    }
}

// ---------------- K3: out[b][i][d] = dinv[i] * sum_j sadj[i][j] * z[j][d] ----------------
// MFMA 16x16x32 f16. Block: 64 i-rows x 64 d, K-loop over 1024 in steps of 64.
// FROM_F32=0: read pre-converted fp16 adj (self-loop already folded in by K1).
// FROM_F32=1: stage fp32 adj directly, converting + adding self-loop (low-ws fallback).
template <int FROM_F32>
__global__ __launch_bounds__(256) void k_agg(const _Float16* __restrict__ adjh,
                                             const float* __restrict__ adjf,
                                             const _Float16* __restrict__ zT,
                                             const float* __restrict__ dinv,
                                             float* __restrict__ out) {
    __shared__ __align__(16) _Float16 adjS[64 * 64];
    __shared__ __align__(16) _Float16 zS[64 * 64];
    const int t = threadIdx.x;
    const int bb = blockIdx.y;
    const int i0 = blockIdx.x * 64;
    const int w = t >> 6, lane = t & 63;
    const int lr = lane & 15, lg = lane >> 4;
    const f32x4 zero = {0.f, 0.f, 0.f, 0.f};
    f32x4 acc[4];
#pragma unroll
    for (int nf = 0; nf < 4; ++nf) acc[nf] = zero;

    for (int kt = 0; kt < 16; ++kt) {
        __syncthreads();
#pragma unroll
        for (int it = 0; it < 2; ++it) {
            const int g = t + (it << 8);
            const int r = g >> 3, c = g & 7;
            if constexpr (FROM_F32) {
                const int gj = kt * 64 + (c << 3);
                const int gi = i0 + r;
                const float4* p = (const float4*)(adjf + (size_t)(bb * NN + gi) * NN + gj);
                const float4 v0 = p[0], v1 = p[1];
                h8 o;
                o[0] = (_Float16)(v0.x + ((gj + 0) == gi ? 1.f : 0.f));
                o[1] = (_Float16)(v0.y + ((gj + 1) == gi ? 1.f : 0.f));
                o[2] = (_Float16)(v0.z + ((gj + 2) == gi ? 1.f : 0.f));
                o[3] = (_Float16)(v0.w + ((gj + 3) == gi ? 1.f : 0.f));
                o[4] = (_Float16)(v1.x + ((gj + 4) == gi ? 1.f : 0.f));
                o[5] = (_Float16)(v1.y + ((gj + 5) == gi ? 1.f : 0.f));
                o[6] = (_Float16)(v1.z + ((gj + 6) == gi ? 1.f : 0.f));
                o[7] = (_Float16)(v1.w + ((gj + 7) == gi ? 1.f : 0.f));
                *(h8*)&adjS[swz(r, c) * 8] = o;
            } else {
                const h8 v = *(const h8*)(adjh + (size_t)(bb * NN + i0 + r) * NN + kt * 64 + (c << 3));
                *(h8*)&adjS[swz(r, c) * 8] = v;
            }
            const h8 vz = *(const h8*)(zT + (size_t)(bb * DD + r) * NN + kt * 64 + (c << 3));
            *(h8*)&zS[swz(r, c) * 8] = vz;
        }
        __syncthreads();
#pragma unroll
        for (int kk = 0; kk < 2; ++kk) {
            const h8 a = *(const h8*)&adjS[swz(w * 16 + lr, kk * 4 + lg) * 8];
#pragma unroll
            for (int nf = 0; nf < 4; ++nf) {
                const h8 bz = *(const h8*)&zS[swz(nf * 16 + lr, kk * 4 + lg) * 8];
                acc[nf] = __builtin_amdgcn_mfma_f32_16x16x32_f16(a, bz, acc[nf], 0, 0, 0);
            }
        }
    }

    const int ib = i0 + w * 16 + lg * 4;   // 4 consecutive output rows (regs 0..3)
    const float4 dv = *(const float4*)&dinv[bb * NN + ib];
#pragma unroll
    for (int nf = 0; nf < 4; ++nf) {
        const int d = nf * 16 + lr;
        float* op = out + (size_t)(bb * NN + ib) * DD + d;
        op[0 * DD] = acc[nf][0] * dv.x;
        op[1 * DD] = acc[nf][1] * dv.y;
        op[2 * DD] = acc[nf][2] * dv.z;
        op[3 * DD] = acc[nf][3] * dv.w;
    }
}

// ---------------- K4: copy weight (second tuple output) ----------------
__global__ __launch_bounds__(256) void k_wcopy(const float* __restrict__ w,
                                               float* __restrict__ ow) {
#pragma unroll
    for (int it = 0; it < 4; ++it) {
        const int idx = threadIdx.x + (it << 8);
        ((float4*)ow)[idx] = ((const float4*)w)[idx];
    }
}

extern "C" void kernel_launch(void* const* d_in, const int* in_sizes, int n_in,
                              void* d_out, int out_size, void* d_ws, size_t ws_size,
                              hipStream_t stream) {
    const float* adj = (const float*)d_in[0];
    const float* att = (const float*)d_in[1];
    const float* wgt = (const float*)d_in[2];
    float* out = (float*)d_out;
    char* ws = (char*)d_ws;

    const size_t adjh_bytes = (size_t)BATCH * NN * NN * 2;   // 128 MiB
    const size_t z_bytes    = (size_t)BATCH * DD * NN * 2;   // 8 MiB
    const size_t dinv_bytes = (size_t)BATCH * NN * 4;        // 256 KiB
    const size_t wt_bytes   = (size_t)DD * DD * 2;           // 8 KiB
    const bool planA = ws_size >= adjh_bytes + z_bytes + dinv_bytes + wt_bytes;

    size_t off = 0;
    _Float16* adjh = nullptr;
    if (planA) { adjh = (_Float16*)ws; off += adjh_bytes; }
    _Float16* zT  = (_Float16*)(ws + off); off += z_bytes;
    float*    dinv = (float*)(ws + off);   off += dinv_bytes;
    _Float16* wt  = (_Float16*)(ws + off);

    k_wt<<<1, 256, 0, stream>>>(wgt, wt);
    k_deg<<<BATCH * NN / 4, 256, 0, stream>>>(adj, adjh, dinv, planA ? 1 : 0);
    k_xw<<<dim3(NN / 128, BATCH), 256, 0, stream>>>(att, wt, dinv, zT);
    if (planA)
        k_agg<0><<<dim3(NN / 64, BATCH), 256, 0, stream>>>(adjh, nullptr, zT, dinv, out);
    else
        k_agg<1><<<dim3(NN / 64, BATCH), 256, 0, stream>>>(nullptr, adj, zT, dinv, out);
    k_wcopy<<<1, 256, 0, stream>>>(wgt, out + (size_t)BATCH * NN * DD);
}

// Round 2
// 109.088 us; speedup vs baseline: 1.0952x; 1.0952x over previous
//
#include <hip/hip_runtime.h>
#include <stdint.h>
#include <stddef.h>

#define BATCH 64
#define NN    1024
#define DD    64   // DIN == DOUT == 64

typedef _Float16 h8 __attribute__((ext_vector_type(8)));
typedef _Float16 h4 __attribute__((ext_vector_type(4)));
typedef float    f32x4 __attribute__((ext_vector_type(4)));

// XOR-swizzled granule slot: tiles are [rows][64 halfs] = [rows][8 granules of 16B].
__device__ __forceinline__ int swz(int row, int gran) {
    return (row << 3) + (gran ^ (row & 7));
}

// ---------------- K0: weight -> WT (transposed fp16) + weight copy to out tail ----------
__global__ __launch_bounds__(256) void k_wt(const float* __restrict__ w,
                                            _Float16* __restrict__ wt,
                                            float* __restrict__ ow) {
#pragma unroll
    for (int it = 0; it < 4; ++it) {
        const int idx = threadIdx.x + (it << 8);   // float4 index 0..1023
        const int k = idx >> 4, d4 = idx & 15;
        const float4 v = ((const float4*)w)[idx];
        wt[(d4 * 4 + 0) * DD + k] = (_Float16)v.x;
        wt[(d4 * 4 + 1) * DD + k] = (_Float16)v.y;
        wt[(d4 * 4 + 2) * DD + k] = (_Float16)v.z;
        wt[(d4 * 4 + 3) * DD + k] = (_Float16)v.w;
        ((float4*)ow)[idx] = v;                     // tuple output #1: weight passthrough
    }
}

// ---------------- K1: z^T[b][d][j] = (att @ W)[j][d], fp16 (NO dinv here) --------------
__global__ __launch_bounds__(256) void k_xw(const float* __restrict__ att,
                                            const _Float16* __restrict__ wt,
                                            _Float16* __restrict__ zT) {
    __shared__ __align__(16) _Float16 attS[128 * 64];
    __shared__ __align__(16) _Float16 wtS[64 * 64];
    const int t = threadIdx.x;
    const int bb = blockIdx.y;
    const int j0 = blockIdx.x * 128;

#pragma unroll
    for (int it = 0; it < 4; ++it) {
        const int g = t + (it << 8);
        const int r = g >> 3, c = g & 7;
        const float4* p = (const float4*)(att + (size_t)(bb * NN + j0 + r) * DD + (c << 3));
        const float4 v0 = p[0], v1 = p[1];
        h8 o;
        o[0] = (_Float16)v0.x; o[1] = (_Float16)v0.y; o[2] = (_Float16)v0.z; o[3] = (_Float16)v0.w;
        o[4] = (_Float16)v1.x; o[5] = (_Float16)v1.y; o[6] = (_Float16)v1.z; o[7] = (_Float16)v1.w;
        *(h8*)&attS[swz(r, c) * 8] = o;
    }
#pragma unroll
    for (int it = 0; it < 2; ++it) {
        const int g = t + (it << 8);
        const int r = g >> 3, c = g & 7;
        const h8 v = *(const h8*)(wt + r * DD + (c << 3));
        *(h8*)&wtS[swz(r, c) * 8] = v;
    }
    __syncthreads();

    const int w = t >> 6, lane = t & 63;
    const int lr = lane & 15, lg = lane >> 4;
    const f32x4 zero = {0.f, 0.f, 0.f, 0.f};
    f32x4 acc[2][4];
#pragma unroll
    for (int mf = 0; mf < 2; ++mf)
#pragma unroll
        for (int nf = 0; nf < 4; ++nf) acc[mf][nf] = zero;

#pragma unroll
    for (int kk = 0; kk < 2; ++kk) {
        h8 a[2], bfr[4];
#pragma unroll
        for (int mf = 0; mf < 2; ++mf)
            a[mf] = *(const h8*)&attS[swz(w * 32 + mf * 16 + lr, kk * 4 + lg) * 8];
#pragma unroll
        for (int nf = 0; nf < 4; ++nf)
            bfr[nf] = *(const h8*)&wtS[swz(nf * 16 + lr, kk * 4 + lg) * 8];
#pragma unroll
        for (int mf = 0; mf < 2; ++mf)
#pragma unroll
            for (int nf = 0; nf < 4; ++nf)
                acc[mf][nf] = __builtin_amdgcn_mfma_f32_16x16x32_f16(a[mf], bfr[nf], acc[mf][nf], 0, 0, 0);
    }

    // D layout: col(d)=lane&15, row(j)=(lane>>4)*4+reg -> 4 consecutive j -> 8B store.
#pragma unroll
    for (int mf = 0; mf < 2; ++mf) {
        const int jb = j0 + w * 32 + mf * 16 + lg * 4;
#pragma unroll
        for (int nf = 0; nf < 4; ++nf) {
            const int d = nf * 16 + lr;
            h4 o;
            o[0] = (_Float16)acc[mf][nf][0];
            o[1] = (_Float16)acc[mf][nf][1];
            o[2] = (_Float16)acc[mf][nf][2];
            o[3] = (_Float16)acc[mf][nf][3];
            *(h4*)(zT + (size_t)(bb * DD + d) * NN + jb) = o;
        }
    }
}

// ---------------- K2: row degrees -> dinv (read-only; warms L3 with adj) ---------------
__global__ __launch_bounds__(256) void k_deg(const float* __restrict__ adj,
                                             float* __restrict__ dinv) {
    const int lane = threadIdx.x & 63;
    const int rowg = blockIdx.x * 4 + (threadIdx.x >> 6);
    const float* rp = adj + (size_t)rowg * NN;
    float s = 0.f;
#pragma unroll
    for (int k = 0; k < 4; ++k) {
        const float4 v = ((const float4*)rp)[lane + (k << 6)];
        s += v.x + v.y + v.z + v.w;
    }
#pragma unroll
    for (int off = 32; off; off >>= 1) s += __shfl_xor(s, off);
    if (lane == 0) dinv[rowg] = 1.f / sqrtf(s);
}

// ---------------- K3: out[b][i][d] = dinv_i * sum_j (adj[i][j]+I) * dinv_j * z[j][d] ----
// fp32 adj read straight from L3 (k_deg just streamed it). dinv_j folded into adjS
// staging; self-loop = one-tile LDS fix-up (+= dinv_i on the diagonal). 2-phase
// prefetch: tile kt+1's global loads issue before tile kt's MFMA.
__global__ __launch_bounds__(256) void k_agg(const float* __restrict__ adj,
                                             const _Float16* __restrict__ zT,
                                             const float* __restrict__ dinv,
                                             float* __restrict__ out) {
    __shared__ __align__(16) _Float16 adjS[64 * 64];
    __shared__ __align__(16) _Float16 zS[64 * 64];
    const int t = threadIdx.x;
    const int bb = blockIdx.y;
    const int i0 = blockIdx.x * 64;
    const int w = t >> 6, lane = t & 63;
    const int lr = lane & 15, lg = lane >> 4;
    const float* dvB = dinv + bb * NN;
    const int ktDiag = i0 >> 6;

    // per-thread granules: g = t + it*256; r = g>>3 (row/d), c = g&7 (j-granule)
    const int r0 = t >> 3, c0 = t & 7;
    const int r1 = (t + 256) >> 3, c1 = t & 7;   // (t+256)&7 == t&7

    float4 pa[2][2];   // prefetched adj fp32 (2 granules x 32B)
    float4 pd[2][2];   // prefetched dinv slices
    h8     pz[2];      // prefetched zT granules

    auto loadT = [&](int kt) {
        const int gj0 = kt * 64 + (c0 << 3);
        const float4* p0 = (const float4*)(adj + (size_t)(bb * NN + i0 + r0) * NN + gj0);
        pa[0][0] = p0[0]; pa[0][1] = p0[1];
        pd[0][0] = *(const float4*)(dvB + gj0);
        pd[0][1] = *(const float4*)(dvB + gj0 + 4);
        pz[0] = *(const h8*)(zT + (size_t)(bb * DD + r0) * NN + gj0);
        const int gj1 = kt * 64 + (c1 << 3);
        const float4* p1 = (const float4*)(adj + (size_t)(bb * NN + i0 + r1) * NN + gj1);
        pa[1][0] = p1[0]; pa[1][1] = p1[1];
        pd[1][0] = *(const float4*)(dvB + gj1);
        pd[1][1] = *(const float4*)(dvB + gj1 + 4);
        pz[1] = *(const h8*)(zT + (size_t)(bb * DD + r1) * NN + gj1);
    };
    auto writeT = [&]() {
#pragma unroll
        for (int it = 0; it < 2; ++it) {
            const int r = it ? r1 : r0, c = it ? c1 : c0;
            h8 o;
            o[0] = (_Float16)(pa[it][0].x * pd[it][0].x);
            o[1] = (_Float16)(pa[it][0].y * pd[it][0].y);
            o[2] = (_Float16)(pa[it][0].z * pd[it][0].z);
            o[3] = (_Float16)(pa[it][0].w * pd[it][0].w);
            o[4] = (_Float16)(pa[it][1].x * pd[it][1].x);
            o[5] = (_Float16)(pa[it][1].y * pd[it][1].y);
            o[6] = (_Float16)(pa[it][1].z * pd[it][1].z);
            o[7] = (_Float16)(pa[it][1].w * pd[it][1].w);
            *(h8*)&adjS[swz(r, c) * 8] = o;
            *(h8*)&zS[swz(r, c) * 8] = pz[it];
        }
    };

    const f32x4 zero = {0.f, 0.f, 0.f, 0.f};
    f32x4 acc[4];
#pragma unroll
    for (int nf = 0; nf < 4; ++nf) acc[nf] = zero;

    loadT(0);
    for (int kt = 0; kt < 16; ++kt) {
        writeT();
        if (kt == ktDiag) {          // uniform condition: diagonal tile fix-up (+I term)
            __syncthreads();
            if (t < 64)
                adjS[swz(t, t >> 3) * 8 + (t & 7)] += (_Float16)dvB[i0 + t];
        }
        __syncthreads();
        if (kt < 15) loadT(kt + 1);  // prefetch overlaps with MFMA below
#pragma unroll
        for (int kk = 0; kk < 2; ++kk) {
            const h8 a = *(const h8*)&adjS[swz(w * 16 + lr, kk * 4 + lg) * 8];
#pragma unroll
            for (int nf = 0; nf < 4; ++nf) {
                const h8 bz = *(const h8*)&zS[swz(nf * 16 + lr, kk * 4 + lg) * 8];
                acc[nf] = __builtin_amdgcn_mfma_f32_16x16x32_f16(a, bz, acc[nf], 0, 0, 0);
            }
        }
        __syncthreads();
    }

    const int ib = i0 + w * 16 + lg * 4;   // 4 consecutive output rows (regs 0..3)
    const float4 dv = *(const float4*)&dinv[bb * NN + ib];
#pragma unroll
    for (int nf = 0; nf < 4; ++nf) {
        const int d = nf * 16 + lr;
        float* op = out + (size_t)(bb * NN + ib) * DD + d;
        op[0 * DD] = acc[nf][0] * dv.x;
        op[1 * DD] = acc[nf][1] * dv.y;
        op[2 * DD] = acc[nf][2] * dv.z;
        op[3 * DD] = acc[nf][3] * dv.w;
    }
}

extern "C" void kernel_launch(void* const* d_in, const int* in_sizes, int n_in,
                              void* d_out, int out_size, void* d_ws, size_t ws_size,
                              hipStream_t stream) {
    const float* adj = (const float*)d_in[0];
    const float* att = (const float*)d_in[1];
    const float* wgt = (const float*)d_in[2];
    float* out = (float*)d_out;
    char* ws = (char*)d_ws;

    size_t off = 0;
    _Float16* zT  = (_Float16*)(ws + off); off += (size_t)BATCH * DD * NN * 2;  // 8 MiB
    float*    dinv = (float*)(ws + off);   off += (size_t)BATCH * NN * 4;       // 256 KiB
    _Float16* wt  = (_Float16*)(ws + off);                                      // 8 KiB

    // Order matters for L3: att/w traffic first, then adj stream (k_deg) immediately
    // followed by k_agg's second adj read (L3-resident).
    k_wt<<<1, 256, 0, stream>>>(wgt, wt, out + (size_t)BATCH * NN * DD);
    k_xw<<<dim3(NN / 128, BATCH), 256, 0, stream>>>(att, wt, zT);
    k_deg<<<BATCH * NN / 4, 256, 0, stream>>>(adj, dinv);
    k_agg<<<dim3(NN / 64, BATCH), 256, 0, stream>>>(adj, zT, dinv, out);
}

// Round 3
// 108.040 us; speedup vs baseline: 1.1059x; 1.0097x over previous
//
#include <hip/hip_runtime.h>
#include <stdint.h>
#include <stddef.h>

#define BATCH 64
#define NN    1024
#define DD    64   // DIN == DOUT == 64

typedef _Float16 h8 __attribute__((ext_vector_type(8)));
typedef _Float16 h4 __attribute__((ext_vector_type(4)));
typedef float    f32x4 __attribute__((ext_vector_type(4)));

// XOR-swizzled granule slot: tiles are [rows][64 halfs] = [rows][8 granules of 16B].
__device__ __forceinline__ int swz(int row, int gran) {
    return (row << 3) + (gran ^ (row & 7));
}

// ---------------- K0: weight -> WT (transposed fp16) + weight copy to out tail ----------
__global__ __launch_bounds__(256) void k_wt(const float* __restrict__ w,
                                            _Float16* __restrict__ wt,
                                            float* __restrict__ ow) {
#pragma unroll
    for (int it = 0; it < 4; ++it) {
        const int idx = threadIdx.x + (it << 8);   // float4 index 0..1023
        const int k = idx >> 4, d4 = idx & 15;
        const float4 v = ((const float4*)w)[idx];
        wt[(d4 * 4 + 0) * DD + k] = (_Float16)v.x;
        wt[(d4 * 4 + 1) * DD + k] = (_Float16)v.y;
        wt[(d4 * 4 + 2) * DD + k] = (_Float16)v.z;
        wt[(d4 * 4 + 3) * DD + k] = (_Float16)v.w;
        ((float4*)ow)[idx] = v;                     // tuple output #1: weight passthrough
    }
}

// ---------------- K1: z^T[b][d][j] = (att @ W)[j][d], fp16 (NO dinv here) --------------
__global__ __launch_bounds__(256) void k_xw(const float* __restrict__ att,
                                            const _Float16* __restrict__ wt,
                                            _Float16* __restrict__ zT) {
    __shared__ __align__(16) _Float16 attS[128 * 64];
    __shared__ __align__(16) _Float16 wtS[64 * 64];
    const int t = threadIdx.x;
    const int bb = blockIdx.y;
    const int j0 = blockIdx.x * 128;

#pragma unroll
    for (int it = 0; it < 4; ++it) {
        const int g = t + (it << 8);
        const int r = g >> 3, c = g & 7;
        const float4* p = (const float4*)(att + (size_t)(bb * NN + j0 + r) * DD + (c << 3));
        const float4 v0 = p[0], v1 = p[1];
        h8 o;
        o[0] = (_Float16)v0.x; o[1] = (_Float16)v0.y; o[2] = (_Float16)v0.z; o[3] = (_Float16)v0.w;
        o[4] = (_Float16)v1.x; o[5] = (_Float16)v1.y; o[6] = (_Float16)v1.z; o[7] = (_Float16)v1.w;
        *(h8*)&attS[swz(r, c) * 8] = o;
    }
#pragma unroll
    for (int it = 0; it < 2; ++it) {
        const int g = t + (it << 8);
        const int r = g >> 3, c = g & 7;
        const h8 v = *(const h8*)(wt + r * DD + (c << 3));
        *(h8*)&wtS[swz(r, c) * 8] = v;
    }
    __syncthreads();

    const int w = t >> 6, lane = t & 63;
    const int lr = lane & 15, lg = lane >> 4;
    const f32x4 zero = {0.f, 0.f, 0.f, 0.f};
    f32x4 acc[2][4];
#pragma unroll
    for (int mf = 0; mf < 2; ++mf)
#pragma unroll
        for (int nf = 0; nf < 4; ++nf) acc[mf][nf] = zero;

#pragma unroll
    for (int kk = 0; kk < 2; ++kk) {
        h8 a[2], bfr[4];
#pragma unroll
        for (int mf = 0; mf < 2; ++mf)
            a[mf] = *(const h8*)&attS[swz(w * 32 + mf * 16 + lr, kk * 4 + lg) * 8];
#pragma unroll
        for (int nf = 0; nf < 4; ++nf)
            bfr[nf] = *(const h8*)&wtS[swz(nf * 16 + lr, kk * 4 + lg) * 8];
#pragma unroll
        for (int mf = 0; mf < 2; ++mf)
#pragma unroll
            for (int nf = 0; nf < 4; ++nf)
                acc[mf][nf] = __builtin_amdgcn_mfma_f32_16x16x32_f16(a[mf], bfr[nf], acc[mf][nf], 0, 0, 0);
    }

    // D layout: col(d)=lane&15, row(j)=(lane>>4)*4+reg -> 4 consecutive j -> 8B store.
#pragma unroll
    for (int mf = 0; mf < 2; ++mf) {
        const int jb = j0 + w * 32 + mf * 16 + lg * 4;
#pragma unroll
        for (int nf = 0; nf < 4; ++nf) {
            const int d = nf * 16 + lr;
            h4 o;
            o[0] = (_Float16)acc[mf][nf][0];
            o[1] = (_Float16)acc[mf][nf][1];
            o[2] = (_Float16)acc[mf][nf][2];
            o[3] = (_Float16)acc[mf][nf][3];
            *(h4*)(zT + (size_t)(bb * DD + d) * NN + jb) = o;
        }
    }
}

// ---------------- K2: row degrees -> dinv (forward stream; leaves adj tail in L3) ------
__global__ __launch_bounds__(256) void k_deg(const float* __restrict__ adj,
                                             float* __restrict__ dinv) {
    const int lane = threadIdx.x & 63;
    const int rowg = blockIdx.x * 4 + (threadIdx.x >> 6);
    const float* rp = adj + (size_t)rowg * NN;
    float s = 0.f;
#pragma unroll
    for (int k = 0; k < 4; ++k) {
        const float4 v = ((const float4*)rp)[lane + (k << 6)];
        s += v.x + v.y + v.z + v.w;
    }
#pragma unroll
    for (int off = 32; off; off >>= 1) s += __shfl_xor(s, off);
    if (lane == 0) dinv[rowg] = 1.f / sqrtf(s);
}

// ---------------- K3: out[b][i][d] = dinv_i * sum_j (adj[i][j]+I) * dinv_j * z[j][d] ----
// BOUSTROPHEDON: blocks consume adj in REVERSE address order, so the tail k_deg just
// left in L3 is hit first; k_agg then leaves the HEAD resident for the next replay's
// k_deg (forward). out stores are nontemporal (never re-read -> don't pollute L3).
__global__ __launch_bounds__(256) void k_agg(const float* __restrict__ adj,
                                             const _Float16* __restrict__ zT,
                                             const float* __restrict__ dinv,
                                             float* __restrict__ out) {
    __shared__ __align__(16) _Float16 adjS[64 * 64];
    __shared__ __align__(16) _Float16 zS[64 * 64];
    const int t = threadIdx.x;
    // reverse flat block id -> (batch, row-tile)
    const int rev = (BATCH * (NN / 64) - 1) - (blockIdx.y * gridDim.x + blockIdx.x);
    const int bb = rev >> 4;
    const int i0 = (rev & 15) << 6;
    const int w = t >> 6, lane = t & 63;
    const int lr = lane & 15, lg = lane >> 4;
    const float* dvB = dinv + bb * NN;
    const int ktDiag = i0 >> 6;

    const int r0 = t >> 3, c0 = t & 7;
    const int r1 = (t + 256) >> 3, c1 = t & 7;

    float4 pa[2][2];
    float4 pd[2][2];
    h8     pz[2];

    auto loadT = [&](int kt) {
        const int gj0 = kt * 64 + (c0 << 3);
        const float4* p0 = (const float4*)(adj + (size_t)(bb * NN + i0 + r0) * NN + gj0);
        pa[0][0] = p0[0]; pa[0][1] = p0[1];
        pd[0][0] = *(const float4*)(dvB + gj0);
        pd[0][1] = *(const float4*)(dvB + gj0 + 4);
        pz[0] = *(const h8*)(zT + (size_t)(bb * DD + r0) * NN + gj0);
        const int gj1 = kt * 64 + (c1 << 3);
        const float4* p1 = (const float4*)(adj + (size_t)(bb * NN + i0 + r1) * NN + gj1);
        pa[1][0] = p1[0]; pa[1][1] = p1[1];
        pd[1][0] = *(const float4*)(dvB + gj1);
        pd[1][1] = *(const float4*)(dvB + gj1 + 4);
        pz[1] = *(const h8*)(zT + (size_t)(bb * DD + r1) * NN + gj1);
    };
    auto writeT = [&]() {
#pragma unroll
        for (int it = 0; it < 2; ++it) {
            const int r = it ? r1 : r0, c = it ? c1 : c0;
            h8 o;
            o[0] = (_Float16)(pa[it][0].x * pd[it][0].x);
            o[1] = (_Float16)(pa[it][0].y * pd[it][0].y);
            o[2] = (_Float16)(pa[it][0].z * pd[it][0].z);
            o[3] = (_Float16)(pa[it][0].w * pd[it][0].w);
            o[4] = (_Float16)(pa[it][1].x * pd[it][1].x);
            o[5] = (_Float16)(pa[it][1].y * pd[it][1].y);
            o[6] = (_Float16)(pa[it][1].z * pd[it][1].z);
            o[7] = (_Float16)(pa[it][1].w * pd[it][1].w);
            *(h8*)&adjS[swz(r, c) * 8] = o;
            *(h8*)&zS[swz(r, c) * 8] = pz[it];
        }
    };

    const f32x4 zero = {0.f, 0.f, 0.f, 0.f};
    f32x4 acc[4];
#pragma unroll
    for (int nf = 0; nf < 4; ++nf) acc[nf] = zero;

    // K-loop also runs high->low j so the very last lines touched are the lowest
    // addresses of this block's 256 KiB adj slice.
    loadT(15);
    for (int kt = 15; kt >= 0; --kt) {
        writeT();
        if (kt == ktDiag) {          // uniform condition: diagonal tile fix-up (+I term)
            __syncthreads();
            if (t < 64)
                adjS[swz(t, t >> 3) * 8 + (t & 7)] += (_Float16)dvB[i0 + t];
        }
        __syncthreads();
        if (kt > 0) loadT(kt - 1);   // prefetch overlaps with MFMA below
#pragma unroll
        for (int kk = 0; kk < 2; ++kk) {
            const h8 a = *(const h8*)&adjS[swz(w * 16 + lr, kk * 4 + lg) * 8];
#pragma unroll
            for (int nf = 0; nf < 4; ++nf) {
                const h8 bz = *(const h8*)&zS[swz(nf * 16 + lr, kk * 4 + lg) * 8];
                acc[nf] = __builtin_amdgcn_mfma_f32_16x16x32_f16(a, bz, acc[nf], 0, 0, 0);
            }
        }
        __syncthreads();
    }

    const int ib = i0 + w * 16 + lg * 4;   // 4 consecutive output rows (regs 0..3)
    const float4 dv = *(const float4*)&dinv[bb * NN + ib];
#pragma unroll
    for (int nf = 0; nf < 4; ++nf) {
        const int d = nf * 16 + lr;
        float* op = out + (size_t)(bb * NN + ib) * DD + d;
        __builtin_nontemporal_store(acc[nf][0] * dv.x, op + 0 * DD);
        __builtin_nontemporal_store(acc[nf][1] * dv.y, op + 1 * DD);
        __builtin_nontemporal_store(acc[nf][2] * dv.z, op + 2 * DD);
        __builtin_nontemporal_store(acc[nf][3] * dv.w, op + 3 * DD);
    }
}

extern "C" void kernel_launch(void* const* d_in, const int* in_sizes, int n_in,
                              void* d_out, int out_size, void* d_ws, size_t ws_size,
                              hipStream_t stream) {
    const float* adj = (const float*)d_in[0];
    const float* att = (const float*)d_in[1];
    const float* wgt = (const float*)d_in[2];
    float* out = (float*)d_out;
    char* ws = (char*)d_ws;

    size_t off = 0;
    _Float16* zT  = (_Float16*)(ws + off); off += (size_t)BATCH * DD * NN * 2;  // 8 MiB
    float*    dinv = (float*)(ws + off);   off += (size_t)BATCH * NN * 4;       // 256 KiB
    _Float16* wt  = (_Float16*)(ws + off);                                      // 8 KiB

    // att/w traffic first; then adj forward stream (k_deg) immediately followed by
    // k_agg's REVERSE adj stream (hits the L3-resident tail; leaves head for the
    // next graph replay's k_deg).
    k_wt<<<1, 256, 0, stream>>>(wgt, wt, out + (size_t)BATCH * NN * DD);
    k_xw<<<dim3(NN / 128, BATCH), 256, 0, stream>>>(att, wt, zT);
    k_deg<<<BATCH * NN / 4, 256, 0, stream>>>(adj, dinv);
    k_agg<<<dim3(NN / 64, BATCH), 256, 0, stream>>>(adj, zT, dinv, out);
}